// Round 1
// baseline (4317.138 us; speedup 1.0000x reference)
//
#include <hip/hip_runtime.h>
#include <math.h>

#define NTOT 32768
#define DMODEL 768
#define BSZ 128
#define NHEAD 16
#define DH 48
#define BETA 0.25f

// ---------------------------------------------------------------------------
// Row stats: mean, rstd (LN, biased var, eps=1e-5), optional l2inv of raw row.
// One wave per row (4 rows per 256-thread block).
// ---------------------------------------------------------------------------
__global__ __launch_bounds__(256)
void row_stats(const float* __restrict__ X, int M, float* __restrict__ mean,
               float* __restrict__ rstd, float* __restrict__ l2inv) {
  const int row = blockIdx.x * 4 + (threadIdx.x >> 6);
  const int lane = threadIdx.x & 63;
  if (row >= M) return;
  const float* x = X + (size_t)row * DMODEL;
  float s = 0.f, s2 = 0.f;
  for (int i = lane; i < DMODEL; i += 64) {
    float v = x[i];
    s += v; s2 += v * v;
  }
#pragma unroll
  for (int off = 32; off; off >>= 1) {
    s  += __shfl_xor(s, off);
    s2 += __shfl_xor(s2, off);
  }
  if (lane == 0) {
    float mu = s * (1.f / DMODEL);
    float var = s2 * (1.f / DMODEL) - mu * mu;
    mean[row] = mu;
    rstd[row] = rsqrtf(var + 1e-5f);
    if (l2inv) l2inv[row] = 1.f / fmaxf(sqrtf(s2), 1e-12f);
  }
}

// ---------------------------------------------------------------------------
// out[m, o] = sum_d LN(A[m])[d] * W[o, d] + bias[o]
// LN applied on the fly: (a - mu)*rstd*g[d] + b[d].
// 64x64 tile, BK=16, 256 threads, 4x4 per thread.
// ---------------------------------------------------------------------------
__global__ __launch_bounds__(256)
void ln_gemm(const float* __restrict__ A, const float* __restrict__ mean,
             const float* __restrict__ rstd, const float* __restrict__ g,
             const float* __restrict__ bln, const float* __restrict__ W,
             const float* __restrict__ bias, float* __restrict__ out) {
  __shared__ float As[16][68];
  __shared__ float Ws[16][68];
  const int t = threadIdx.x;
  const int m0 = blockIdx.y << 6, n0 = blockIdx.x << 6;
  const int tm = t >> 4, tn = t & 15;
  const int lr = t >> 2;          // 0..63 tile row for loads
  const int lk = (t & 3) << 2;    // 0,4,8,12
  const float muL = mean[m0 + lr];
  const float rsL = rstd[m0 + lr];
  float acc[4][4] = {};
  for (int k0 = 0; k0 < DMODEL; k0 += 16) {
    float4 a4 = *(const float4*)(A + (size_t)(m0 + lr) * DMODEL + k0 + lk);
    float4 g4 = *(const float4*)(g + k0 + lk);
    float4 b4 = *(const float4*)(bln + k0 + lk);
    As[lk + 0][lr] = (a4.x - muL) * rsL * g4.x + b4.x;
    As[lk + 1][lr] = (a4.y - muL) * rsL * g4.y + b4.y;
    As[lk + 2][lr] = (a4.z - muL) * rsL * g4.z + b4.z;
    As[lk + 3][lr] = (a4.w - muL) * rsL * g4.w + b4.w;
    float4 w4 = *(const float4*)(W + (size_t)(n0 + lr) * DMODEL + k0 + lk);
    Ws[lk + 0][lr] = w4.x;
    Ws[lk + 1][lr] = w4.y;
    Ws[lk + 2][lr] = w4.z;
    Ws[lk + 3][lr] = w4.w;
    __syncthreads();
#pragma unroll
    for (int kk = 0; kk < 16; kk++) {
      const float4 av = *(const float4*)(&As[kk][tm * 4]);
      const float4 bv = *(const float4*)(&Ws[kk][tn * 4]);
      const float a[4] = {av.x, av.y, av.z, av.w};
      const float b[4] = {bv.x, bv.y, bv.z, bv.w};
#pragma unroll
      for (int i = 0; i < 4; i++)
#pragma unroll
        for (int j = 0; j < 4; j++) acc[i][j] += a[i] * b[j];
    }
    __syncthreads();
  }
  const float4 bia = *(const float4*)(bias + n0 + tn * 4);
  const float bb[4] = {bia.x, bia.y, bia.z, bia.w};
#pragma unroll
  for (int i = 0; i < 4; i++) {
    const int m = m0 + tm * 4 + i;
    float4 o4;
    o4.x = acc[i][0] + bb[0];
    o4.y = acc[i][1] + bb[1];
    o4.z = acc[i][2] + bb[2];
    o4.w = acc[i][3] + bb[3];
    *(float4*)(out + (size_t)m * DMODEL + n0 + tn * 4) = o4;
  }
}

// ---------------------------------------------------------------------------
// Plain small GEMM: out = act(A @ W^T + bias [+ add])
// ---------------------------------------------------------------------------
__global__ __launch_bounds__(256)
void gemm_bias(const float* __restrict__ A, const float* __restrict__ W,
               const float* __restrict__ bias, const float* __restrict__ add,
               float* __restrict__ out, int relu) {
  __shared__ float As[16][68];
  __shared__ float Ws[16][68];
  const int t = threadIdx.x;
  const int m0 = blockIdx.y << 6, n0 = blockIdx.x << 6;
  const int tm = t >> 4, tn = t & 15;
  const int lr = t >> 2;
  const int lk = (t & 3) << 2;
  float acc[4][4] = {};
  for (int k0 = 0; k0 < DMODEL; k0 += 16) {
    float4 a4 = *(const float4*)(A + (size_t)(m0 + lr) * DMODEL + k0 + lk);
    As[lk + 0][lr] = a4.x;
    As[lk + 1][lr] = a4.y;
    As[lk + 2][lr] = a4.z;
    As[lk + 3][lr] = a4.w;
    float4 w4 = *(const float4*)(W + (size_t)(n0 + lr) * DMODEL + k0 + lk);
    Ws[lk + 0][lr] = w4.x;
    Ws[lk + 1][lr] = w4.y;
    Ws[lk + 2][lr] = w4.z;
    Ws[lk + 3][lr] = w4.w;
    __syncthreads();
#pragma unroll
    for (int kk = 0; kk < 16; kk++) {
      const float4 av = *(const float4*)(&As[kk][tm * 4]);
      const float4 bv = *(const float4*)(&Ws[kk][tn * 4]);
      const float a[4] = {av.x, av.y, av.z, av.w};
      const float b[4] = {bv.x, bv.y, bv.z, bv.w};
#pragma unroll
      for (int i = 0; i < 4; i++)
#pragma unroll
        for (int j = 0; j < 4; j++) acc[i][j] += a[i] * b[j];
    }
    __syncthreads();
  }
  const float4 bia = *(const float4*)(bias + n0 + tn * 4);
  const float bb[4] = {bia.x, bia.y, bia.z, bia.w};
#pragma unroll
  for (int i = 0; i < 4; i++) {
    const int m = m0 + tm * 4 + i;
    float v[4];
#pragma unroll
    for (int j = 0; j < 4; j++) v[j] = acc[i][j] + bb[j];
    if (add) {
      const float4 a4 = *(const float4*)(add + (size_t)m * DMODEL + n0 + tn * 4);
      v[0] += a4.x; v[1] += a4.y; v[2] += a4.z; v[3] += a4.w;
    }
    if (relu) {
#pragma unroll
      for (int j = 0; j < 4; j++) v[j] = fmaxf(v[j], 0.f);
    }
    float4 o4 = {v[0], v[1], v[2], v[3]};
    *(float4*)(out + (size_t)m * DMODEL + n0 + tn * 4) = o4;
  }
}

// ---------------------------------------------------------------------------
// logits[m, n] = 20 * ainv[m] * binv[n] * (rq[m] . mb[n])
// ---------------------------------------------------------------------------
__global__ __launch_bounds__(256)
void logits_gemm(const float* __restrict__ A, const float* __restrict__ Bm,
                 const float* __restrict__ ainv, const float* __restrict__ binv,
                 float* __restrict__ out) {
  __shared__ float As[16][68];
  __shared__ float Ws[16][68];
  const int t = threadIdx.x;
  const int m0 = blockIdx.y << 6, n0 = blockIdx.x << 6;
  const int tm = t >> 4, tn = t & 15;
  const int lr = t >> 2;
  const int lk = (t & 3) << 2;
  float acc[4][4] = {};
  for (int k0 = 0; k0 < DMODEL; k0 += 16) {
    float4 a4 = *(const float4*)(A + (size_t)(m0 + lr) * DMODEL + k0 + lk);
    As[lk + 0][lr] = a4.x;
    As[lk + 1][lr] = a4.y;
    As[lk + 2][lr] = a4.z;
    As[lk + 3][lr] = a4.w;
    float4 w4 = *(const float4*)(Bm + (size_t)(n0 + lr) * DMODEL + k0 + lk);
    Ws[lk + 0][lr] = w4.x;
    Ws[lk + 1][lr] = w4.y;
    Ws[lk + 2][lr] = w4.z;
    Ws[lk + 3][lr] = w4.w;
    __syncthreads();
#pragma unroll
    for (int kk = 0; kk < 16; kk++) {
      const float4 av = *(const float4*)(&As[kk][tm * 4]);
      const float4 bv = *(const float4*)(&Ws[kk][tn * 4]);
      const float a[4] = {av.x, av.y, av.z, av.w};
      const float b[4] = {bv.x, bv.y, bv.z, bv.w};
#pragma unroll
      for (int i = 0; i < 4; i++)
#pragma unroll
        for (int j = 0; j < 4; j++) acc[i][j] += a[i] * b[j];
    }
    __syncthreads();
  }
  const float4 bi4 = *(const float4*)(binv + n0 + tn * 4);
  const float bi[4] = {bi4.x, bi4.y, bi4.z, bi4.w};
#pragma unroll
  for (int i = 0; i < 4; i++) {
    const int m = m0 + tm * 4 + i;
    const float sa = 20.f * ainv[m];
    float4 o4;
    o4.x = acc[i][0] * sa * bi[0];
    o4.y = acc[i][1] * sa * bi[1];
    o4.z = acc[i][2] * sa * bi[2];
    o4.w = acc[i][3] * sa * bi[3];
    *(float4*)(out + (size_t)m * NTOT + n0 + tn * 4) = o4;
  }
}

// ---------------------------------------------------------------------------
// Hopfield flash partials. Grid (NCHUNK=32, H=16), 256 threads.
// Lane = b (0..127) x half (0..1). Each thread: online softmax over its rows.
// K rows are wave-uniform -> uniform-address loads, no LDS, no barriers.
// Writes partial (m, l, o[48]) at [( (h*32+chunk)*2 + half )*128 + b]*50.
// ---------------------------------------------------------------------------
#define NCHUNK 32
#define NCROWS (NTOT / NCHUNK)  // 1024

__global__ __launch_bounds__(256)
void hopfield_partial(const float* __restrict__ kbuf, const float* __restrict__ vbuf,
                      const float* __restrict__ xi, float* __restrict__ part,
                      int useV) {
  const int h = blockIdx.y;
  const int chunk = blockIdx.x;
  const int t = threadIdx.x;
  const int b = t & 127;
  const int half = __builtin_amdgcn_readfirstlane(t >> 7);  // wave-uniform
  float x[DH];
  {
    const float* xp = xi + (size_t)b * DMODEL + h * DH;
#pragma unroll
    for (int j4 = 0; j4 < 12; j4++) {
      float4 v4 = *(const float4*)(xp + j4 * 4);
      x[j4 * 4 + 0] = v4.x; x[j4 * 4 + 1] = v4.y;
      x[j4 * 4 + 2] = v4.z; x[j4 * 4 + 3] = v4.w;
    }
  }
  float m = -1e30f, l = 0.f;
  float o[DH];
#pragma unroll
  for (int j = 0; j < DH; j++) o[j] = 0.f;

  const size_t base = (size_t)(chunk * NCROWS) * DMODEL + h * DH;
  for (int i = 0; i < NCROWS / 2; i++) {
    const int r = (i << 1) | half;  // wave-uniform row
    const float* kp = kbuf + base + (size_t)r * DMODEL;
    float kr[DH];
#pragma unroll
    for (int j4 = 0; j4 < 12; j4++) {
      float4 v4 = *(const float4*)(kp + j4 * 4);
      kr[j4 * 4 + 0] = v4.x; kr[j4 * 4 + 1] = v4.y;
      kr[j4 * 4 + 2] = v4.z; kr[j4 * 4 + 3] = v4.w;
    }
    float s = 0.f;
#pragma unroll
    for (int j = 0; j < DH; j++) s += x[j] * kr[j];
    s *= BETA;
    const float nm = fmaxf(m, s);
    const float sc = __expf(m - nm);
    const float p = __expf(s - nm);
    m = nm;
    l = l * sc + p;
    if (!useV) {
#pragma unroll
      for (int j = 0; j < DH; j++) o[j] = o[j] * sc + p * kr[j];
    } else {
      const float* vp = vbuf + base + (size_t)r * DMODEL;
#pragma unroll
      for (int j4 = 0; j4 < 12; j4++) {
        float4 v4 = *(const float4*)(vp + j4 * 4);
        o[j4 * 4 + 0] = o[j4 * 4 + 0] * sc + p * v4.x;
        o[j4 * 4 + 1] = o[j4 * 4 + 1] * sc + p * v4.y;
        o[j4 * 4 + 2] = o[j4 * 4 + 2] * sc + p * v4.z;
        o[j4 * 4 + 3] = o[j4 * 4 + 3] * sc + p * v4.w;
      }
    }
  }
  const size_t pidx = ((size_t)(h * NCHUNK + chunk) * 2 + half) * BSZ + b;
  float* pp = part + pidx * 50;
  pp[0] = m;
  pp[1] = l;
#pragma unroll
  for (int j = 0; j < DH; j++) pp[2 + j] = o[j];
}

// ---------------------------------------------------------------------------
// Combine 64 partials per (b,h). Grid = B*H blocks of 64 threads.
// ---------------------------------------------------------------------------
__global__ __launch_bounds__(64)
void hopfield_combine(const float* __restrict__ part, float* __restrict__ dst) {
  const int bh = blockIdx.x;  // h*128 + b
  const int h = bh >> 7, b = bh & 127;
  const int lane = threadIdx.x;
  __shared__ float w[64];
  const float* pb = part + ((size_t)h * 64 * BSZ + b) * 50;
  const size_t pstride = (size_t)BSZ * 50;
  const float mp = pb[lane * pstride];
  float m = mp;
#pragma unroll
  for (int off = 32; off; off >>= 1) m = fmaxf(m, __shfl_xor(m, off));
  const float lp = pb[lane * pstride + 1];
  const float wp = __expf(mp - m);
  w[lane] = wp;
  float L = lp * wp;
#pragma unroll
  for (int off = 32; off; off >>= 1) L += __shfl_xor(L, off);
  __syncthreads();
  if (lane < DH) {
    float o = 0.f;
    for (int p = 0; p < 64; p++) o += pb[p * pstride + 2 + lane] * w[p];
    dst[(size_t)b * DMODEL + h * DH + lane] = o / L;
  }
}

// ---------------------------------------------------------------------------
// Top-4 per row with jax tie-breaking (lower index first). 128 blocks x 256.
// ---------------------------------------------------------------------------
__global__ __launch_bounds__(256)
void topk_kernel(const float* __restrict__ logits, float* __restrict__ outIdx) {
  const int b = blockIdx.x;
  const int t = threadIdx.x;
  const float* row = logits + (size_t)b * NTOT;
  float v[4] = {-1e30f, -1e30f, -1e30f, -1e30f};
  int id[4] = {0x7fffffff, 0x7fffffff, 0x7fffffff, 0x7fffffff};
  for (int n = t; n < NTOT; n += 256) {
    const float x = row[n];
    if (x > v[3]) {
      v[3] = x; id[3] = n;
#pragma unroll
      for (int s = 3; s > 0; s--) {
        const bool sw = (v[s] > v[s - 1]) || (v[s] == v[s - 1] && id[s] < id[s - 1]);
        if (sw) {
          float tv = v[s]; v[s] = v[s - 1]; v[s - 1] = tv;
          int ti = id[s]; id[s] = id[s - 1]; id[s - 1] = ti;
        }
      }
    }
  }
  __shared__ float sv[256][4];
  __shared__ int si[256][4];
#pragma unroll
  for (int j = 0; j < 4; j++) { sv[t][j] = v[j]; si[t][j] = id[j]; }
  for (int str = 128; str >= 1; str >>= 1) {
    __syncthreads();
    if (t < str) {
      float a[4], c[4];
      int ai[4], ci[4];
#pragma unroll
      for (int j = 0; j < 4; j++) {
        a[j] = sv[t][j]; ai[j] = si[t][j];
        c[j] = sv[t + str][j]; ci[j] = si[t + str][j];
      }
      float rv[4]; int ri[4];
      int p = 0, q = 0;
#pragma unroll
      for (int oo = 0; oo < 4; oo++) {
        const bool ta = (a[p] > c[q]) || (a[p] == c[q] && ai[p] < ci[q]);
        if (ta) { rv[oo] = a[p]; ri[oo] = ai[p]; p++; }
        else    { rv[oo] = c[q]; ri[oo] = ci[q]; q++; }
      }
#pragma unroll
      for (int j = 0; j < 4; j++) { sv[t][j] = rv[j]; si[t][j] = ri[j]; }
    }
  }
  if (t == 0) {
#pragma unroll
    for (int j = 0; j < 4; j++) outIdx[b * 4 + j] = (float)si[0][j];
  }
}

// ---------------------------------------------------------------------------
extern "C" void kernel_launch(void* const* d_in, const int* in_sizes, int n_in,
                              void* d_out, int out_size, void* d_ws, size_t ws_size,
                              hipStream_t stream) {
  const float* qe    = (const float*)d_in[0];
  const float* mb    = (const float*)d_in[1];
  const float* ln_kg = (const float*)d_in[2];
  const float* ln_kb = (const float*)d_in[3];
  const float* ln_qg = (const float*)d_in[4];
  const float* ln_qb = (const float*)d_in[5];
  const float* ln_vg = (const float*)d_in[6];
  const float* ln_vb = (const float*)d_in[7];
  const float* Wq = (const float*)d_in[8];
  const float* bq = (const float*)d_in[9];
  const float* Wk = (const float*)d_in[10];
  const float* bk = (const float*)d_in[11];
  const float* Wv = (const float*)d_in[12];
  const float* bv = (const float*)d_in[13];
  const float* Wo = (const float*)d_in[14];
  const float* bo = (const float*)d_in[15];
  const float* W1 = (const float*)d_in[16];
  const float* b1 = (const float*)d_in[17];
  const float* W2 = (const float*)d_in[18];
  const float* b2 = (const float*)d_in[19];

  float* out = (float*)d_out;           // [0..511] top indices (as float), then logits
  float* logits = out + BSZ * 4;

  float* ws = (float*)d_ws;
  size_t off = 0;
  auto alloc = [&](size_t n) { float* p = ws + off; off += n; return p; };
  float* mb_mean = alloc(NTOT);
  float* mb_rstd = alloc(NTOT);
  float* mb_l2i  = alloc(NTOT);
  float* q_mean  = alloc(128);
  float* q_rstd  = alloc(128);
  float* rq_mean = alloc(128);
  float* rq_rstd = alloc(128);
  float* rq_inv  = alloc(128);
  float* kbuf = alloc((size_t)NTOT * DMODEL);
  float* vbuf = alloc((size_t)NTOT * DMODEL);
  float* xi   = alloc((size_t)BSZ * DMODEL);
  float* conv = alloc((size_t)BSZ * DMODEL);
  float* comb = alloc((size_t)BSZ * DMODEL);
  float* h1   = alloc((size_t)BSZ * DMODEL);
  float* rq   = alloc((size_t)BSZ * DMODEL);
  float* part = alloc((size_t)NHEAD * 64 * BSZ * 50);
  (void)ws_size; (void)in_sizes; (void)n_in; (void)out_size;

  // 1. stats
  row_stats<<<NTOT / 4, 256, 0, stream>>>(mb, NTOT, mb_mean, mb_rstd, mb_l2i);
  row_stats<<<BSZ / 4, 256, 0, stream>>>(qe, BSZ, q_mean, q_rstd, nullptr);

  // 2. k, v, q projections (LN fused)
  ln_gemm<<<dim3(DMODEL / 64, NTOT / 64), 256, 0, stream>>>(
      mb, mb_mean, mb_rstd, ln_kg, ln_kb, Wk, bk, kbuf);
  ln_gemm<<<dim3(DMODEL / 64, NTOT / 64), 256, 0, stream>>>(
      mb, mb_mean, mb_rstd, ln_vg, ln_vb, Wv, bv, vbuf);
  ln_gemm<<<dim3(DMODEL / 64, BSZ / 64), 256, 0, stream>>>(
      qe, q_mean, q_rstd, ln_qg, ln_qb, Wq, bq, xi);

  // 3. Hopfield iterations: 5 updates (value = k), then readout (value = v)
  for (int r = 0; r < 6; r++) {
    const int useV = (r == 5) ? 1 : 0;
    hopfield_partial<<<dim3(NCHUNK, NHEAD), 256, 0, stream>>>(kbuf, vbuf, xi, part, useV);
    hopfield_combine<<<BSZ * NHEAD, 64, 0, stream>>>(part, useV ? conv : xi);
  }

  // 4. readout MLP: combined = qe + conv@Wo^T + bo; h1 = relu(combined@W1^T+b1); rq = h1@W2^T+b2
  gemm_bias<<<dim3(DMODEL / 64, BSZ / 64), 256, 0, stream>>>(conv, Wo, bo, qe, comb, 0);
  gemm_bias<<<dim3(DMODEL / 64, BSZ / 64), 256, 0, stream>>>(comb, W1, b1, nullptr, h1, 1);
  gemm_bias<<<dim3(DMODEL / 64, BSZ / 64), 256, 0, stream>>>(h1, W2, b2, nullptr, rq, 0);

  // 5. cosine logits
  row_stats<<<BSZ / 4, 256, 0, stream>>>(rq, BSZ, rq_mean, rq_rstd, rq_inv);
  logits_gemm<<<dim3(NTOT / 64, BSZ / 64), 256, 0, stream>>>(rq, mb, rq_inv, mb_l2i, logits);

  // 6. top-4 indices (written as float)
  topk_kernel<<<BSZ, 256, 0, stream>>>(logits, out);
}

// Round 4
// 2263.124 us; speedup vs baseline: 1.9076x; 1.9076x over previous
//
#include <hip/hip_runtime.h>
#include <math.h>

#define NTOT 32768
#define DMODEL 768
#define BSZ 128
#define NHEAD 16
#define DH 48
#define BETA 0.25f

typedef _Float16 f16;
typedef f16 f16x8 __attribute__((ext_vector_type(8)));
typedef f16 f16x4 __attribute__((ext_vector_type(4)));
typedef float f32x4 __attribute__((ext_vector_type(4)));

// ---------------------------------------------------------------------------
// Row stats: mean, rstd (LN, biased var, eps=1e-5), optional l2inv of raw row.
// ---------------------------------------------------------------------------
__global__ __launch_bounds__(256)
void row_stats(const float* __restrict__ X, int M, float* __restrict__ mean,
               float* __restrict__ rstd, float* __restrict__ l2inv) {
  const int row = blockIdx.x * 4 + (threadIdx.x >> 6);
  const int lane = threadIdx.x & 63;
  if (row >= M) return;
  const float* x = X + (size_t)row * DMODEL;
  float s = 0.f, s2 = 0.f;
  for (int i = lane; i < DMODEL; i += 64) {
    float v = x[i];
    s += v; s2 += v * v;
  }
#pragma unroll
  for (int off = 32; off; off >>= 1) {
    s  += __shfl_xor(s, off);
    s2 += __shfl_xor(s2, off);
  }
  if (lane == 0) {
    float mu = s * (1.f / DMODEL);
    float var = s2 * (1.f / DMODEL) - mu * mu;
    mean[row] = mu;
    rstd[row] = rsqrtf(var + 1e-5f);
    if (l2inv) l2inv[row] = 1.f / fmaxf(sqrtf(s2), 1e-12f);
  }
}

// ---------------------------------------------------------------------------
// LN-fused GEMM, fp32 compute, output = fp16 (hi, lo) pair.
// out[m,o] = sum_d LN(A[m])[d]*W[o,d] + bias[o]; hi=(f16)v, lo=(f16)(v-hi).
// ---------------------------------------------------------------------------
__global__ __launch_bounds__(256)
void ln_gemm_split(const float* __restrict__ A, const float* __restrict__ mean,
                   const float* __restrict__ rstd, const float* __restrict__ g,
                   const float* __restrict__ bln, const float* __restrict__ W,
                   const float* __restrict__ bias, f16* __restrict__ outHi,
                   f16* __restrict__ outLo) {
  __shared__ float As[16][68];
  __shared__ float Ws[16][68];
  const int t = threadIdx.x;
  const int m0 = blockIdx.y << 6, n0 = blockIdx.x << 6;
  const int tm = t >> 4, tn = t & 15;
  const int lr = t >> 2;
  const int lk = (t & 3) << 2;
  const float muL = mean[m0 + lr];
  const float rsL = rstd[m0 + lr];
  float acc[4][4] = {};
  for (int k0 = 0; k0 < DMODEL; k0 += 16) {
    float4 a4 = *(const float4*)(A + (size_t)(m0 + lr) * DMODEL + k0 + lk);
    float4 g4 = *(const float4*)(g + k0 + lk);
    float4 b4 = *(const float4*)(bln + k0 + lk);
    As[lk + 0][lr] = (a4.x - muL) * rsL * g4.x + b4.x;
    As[lk + 1][lr] = (a4.y - muL) * rsL * g4.y + b4.y;
    As[lk + 2][lr] = (a4.z - muL) * rsL * g4.z + b4.z;
    As[lk + 3][lr] = (a4.w - muL) * rsL * g4.w + b4.w;
    float4 w4 = *(const float4*)(W + (size_t)(n0 + lr) * DMODEL + k0 + lk);
    Ws[lk + 0][lr] = w4.x;
    Ws[lk + 1][lr] = w4.y;
    Ws[lk + 2][lr] = w4.z;
    Ws[lk + 3][lr] = w4.w;
    __syncthreads();
#pragma unroll
    for (int kk = 0; kk < 16; kk++) {
      const float4 av = *(const float4*)(&As[kk][tm * 4]);
      const float4 bv = *(const float4*)(&Ws[kk][tn * 4]);
      const float a[4] = {av.x, av.y, av.z, av.w};
      const float b[4] = {bv.x, bv.y, bv.z, bv.w};
#pragma unroll
      for (int i = 0; i < 4; i++)
#pragma unroll
        for (int j = 0; j < 4; j++) acc[i][j] += a[i] * b[j];
    }
    __syncthreads();
  }
  const float4 bia = *(const float4*)(bias + n0 + tn * 4);
  const float bb[4] = {bia.x, bia.y, bia.z, bia.w};
#pragma unroll
  for (int i = 0; i < 4; i++) {
    const int m = m0 + tm * 4 + i;
    f16x4 h4, l4;
#pragma unroll
    for (int j = 0; j < 4; j++) {
      const float v = acc[i][j] + bb[j];
      const f16 hv = (f16)v;
      h4[j] = hv;
      l4[j] = (f16)(v - (float)hv);
    }
    *(f16x4*)(outHi + (size_t)m * DMODEL + n0 + tn * 4) = h4;
    *(f16x4*)(outLo + (size_t)m * DMODEL + n0 + tn * 4) = l4;
  }
}

// ---------------------------------------------------------------------------
// LN-fused GEMM, fp32 output (for q projection).
// ---------------------------------------------------------------------------
__global__ __launch_bounds__(256)
void ln_gemm_f32(const float* __restrict__ A, const float* __restrict__ mean,
                 const float* __restrict__ rstd, const float* __restrict__ g,
                 const float* __restrict__ bln, const float* __restrict__ W,
                 const float* __restrict__ bias, float* __restrict__ out) {
  __shared__ float As[16][68];
  __shared__ float Ws[16][68];
  const int t = threadIdx.x;
  const int m0 = blockIdx.y << 6, n0 = blockIdx.x << 6;
  const int tm = t >> 4, tn = t & 15;
  const int lr = t >> 2;
  const int lk = (t & 3) << 2;
  const float muL = mean[m0 + lr];
  const float rsL = rstd[m0 + lr];
  float acc[4][4] = {};
  for (int k0 = 0; k0 < DMODEL; k0 += 16) {
    float4 a4 = *(const float4*)(A + (size_t)(m0 + lr) * DMODEL + k0 + lk);
    float4 g4 = *(const float4*)(g + k0 + lk);
    float4 b4 = *(const float4*)(bln + k0 + lk);
    As[lk + 0][lr] = (a4.x - muL) * rsL * g4.x + b4.x;
    As[lk + 1][lr] = (a4.y - muL) * rsL * g4.y + b4.y;
    As[lk + 2][lr] = (a4.z - muL) * rsL * g4.z + b4.z;
    As[lk + 3][lr] = (a4.w - muL) * rsL * g4.w + b4.w;
    float4 w4 = *(const float4*)(W + (size_t)(n0 + lr) * DMODEL + k0 + lk);
    Ws[lk + 0][lr] = w4.x;
    Ws[lk + 1][lr] = w4.y;
    Ws[lk + 2][lr] = w4.z;
    Ws[lk + 3][lr] = w4.w;
    __syncthreads();
#pragma unroll
    for (int kk = 0; kk < 16; kk++) {
      const float4 av = *(const float4*)(&As[kk][tm * 4]);
      const float4 bv = *(const float4*)(&Ws[kk][tn * 4]);
      const float a[4] = {av.x, av.y, av.z, av.w};
      const float b[4] = {bv.x, bv.y, bv.z, bv.w};
#pragma unroll
      for (int i = 0; i < 4; i++)
#pragma unroll
        for (int j = 0; j < 4; j++) acc[i][j] += a[i] * b[j];
    }
    __syncthreads();
  }
  const float4 bia = *(const float4*)(bias + n0 + tn * 4);
  const float bb[4] = {bia.x, bia.y, bia.z, bia.w};
#pragma unroll
  for (int i = 0; i < 4; i++) {
    const int m = m0 + tm * 4 + i;
    float4 o4;
    o4.x = acc[i][0] + bb[0];
    o4.y = acc[i][1] + bb[1];
    o4.z = acc[i][2] + bb[2];
    o4.w = acc[i][3] + bb[3];
    *(float4*)(out + (size_t)m * DMODEL + n0 + tn * 4) = o4;
  }
}

// ---------------------------------------------------------------------------
// Plain small GEMM: out = act(A @ W^T + bias [+ add])
// ---------------------------------------------------------------------------
__global__ __launch_bounds__(256)
void gemm_bias(const float* __restrict__ A, const float* __restrict__ W,
               const float* __restrict__ bias, const float* __restrict__ add,
               float* __restrict__ out, int relu) {
  __shared__ float As[16][68];
  __shared__ float Ws[16][68];
  const int t = threadIdx.x;
  const int m0 = blockIdx.y << 6, n0 = blockIdx.x << 6;
  const int tm = t >> 4, tn = t & 15;
  const int lr = t >> 2;
  const int lk = (t & 3) << 2;
  float acc[4][4] = {};
  for (int k0 = 0; k0 < DMODEL; k0 += 16) {
    float4 a4 = *(const float4*)(A + (size_t)(m0 + lr) * DMODEL + k0 + lk);
    As[lk + 0][lr] = a4.x;
    As[lk + 1][lr] = a4.y;
    As[lk + 2][lr] = a4.z;
    As[lk + 3][lr] = a4.w;
    float4 w4 = *(const float4*)(W + (size_t)(n0 + lr) * DMODEL + k0 + lk);
    Ws[lk + 0][lr] = w4.x;
    Ws[lk + 1][lr] = w4.y;
    Ws[lk + 2][lr] = w4.z;
    Ws[lk + 3][lr] = w4.w;
    __syncthreads();
#pragma unroll
    for (int kk = 0; kk < 16; kk++) {
      const float4 av = *(const float4*)(&As[kk][tm * 4]);
      const float4 bv = *(const float4*)(&Ws[kk][tn * 4]);
      const float a[4] = {av.x, av.y, av.z, av.w};
      const float b[4] = {bv.x, bv.y, bv.z, bv.w};
#pragma unroll
      for (int i = 0; i < 4; i++)
#pragma unroll
        for (int j = 0; j < 4; j++) acc[i][j] += a[i] * b[j];
    }
    __syncthreads();
  }
  const float4 bia = *(const float4*)(bias + n0 + tn * 4);
  const float bb[4] = {bia.x, bia.y, bia.z, bia.w};
#pragma unroll
  for (int i = 0; i < 4; i++) {
    const int m = m0 + tm * 4 + i;
    float v[4];
#pragma unroll
    for (int j = 0; j < 4; j++) v[j] = acc[i][j] + bb[j];
    if (add) {
      const float4 a4 = *(const float4*)(add + (size_t)m * DMODEL + n0 + tn * 4);
      v[0] += a4.x; v[1] += a4.y; v[2] += a4.z; v[3] += a4.w;
    }
    if (relu) {
#pragma unroll
      for (int j = 0; j < 4; j++) v[j] = fmaxf(v[j], 0.f);
    }
    float4 o4 = {v[0], v[1], v[2], v[3]};
    *(float4*)(out + (size_t)m * DMODEL + n0 + tn * 4) = o4;
  }
}

// ---------------------------------------------------------------------------
// logits[m, n] = 20 * ainv[m] * binv[n] * (rq[m] . mb[n])
// ---------------------------------------------------------------------------
__global__ __launch_bounds__(256)
void logits_gemm(const float* __restrict__ A, const float* __restrict__ Bm,
                 const float* __restrict__ ainv, const float* __restrict__ binv,
                 float* __restrict__ out) {
  __shared__ float As[16][68];
  __shared__ float Ws[16][68];
  const int t = threadIdx.x;
  const int m0 = blockIdx.y << 6, n0 = blockIdx.x << 6;
  const int tm = t >> 4, tn = t & 15;
  const int lr = t >> 2;
  const int lk = (t & 3) << 2;
  float acc[4][4] = {};
  for (int k0 = 0; k0 < DMODEL; k0 += 16) {
    float4 a4 = *(const float4*)(A + (size_t)(m0 + lr) * DMODEL + k0 + lk);
    As[lk + 0][lr] = a4.x;
    As[lk + 1][lr] = a4.y;
    As[lk + 2][lr] = a4.z;
    As[lk + 3][lr] = a4.w;
    float4 w4 = *(const float4*)(Bm + (size_t)(n0 + lr) * DMODEL + k0 + lk);
    Ws[lk + 0][lr] = w4.x;
    Ws[lk + 1][lr] = w4.y;
    Ws[lk + 2][lr] = w4.z;
    Ws[lk + 3][lr] = w4.w;
    __syncthreads();
#pragma unroll
    for (int kk = 0; kk < 16; kk++) {
      const float4 av = *(const float4*)(&As[kk][tm * 4]);
      const float4 bv = *(const float4*)(&Ws[kk][tn * 4]);
      const float a[4] = {av.x, av.y, av.z, av.w};
      const float b[4] = {bv.x, bv.y, bv.z, bv.w};
#pragma unroll
      for (int i = 0; i < 4; i++)
#pragma unroll
        for (int j = 0; j < 4; j++) acc[i][j] += a[i] * b[j];
    }
    __syncthreads();
  }
  const float4 bi4 = *(const float4*)(binv + n0 + tn * 4);
  const float bi[4] = {bi4.x, bi4.y, bi4.z, bi4.w};
#pragma unroll
  for (int i = 0; i < 4; i++) {
    const int m = m0 + tm * 4 + i;
    const float sa = 20.f * ainv[m];
    float4 o4;
    o4.x = acc[i][0] * sa * bi[0];
    o4.y = acc[i][1] * sa * bi[1];
    o4.z = acc[i][2] * sa * bi[2];
    o4.w = acc[i][3] * sa * bi[3];
    *(float4*)(out + (size_t)m * NTOT + n0 + tn * 4) = o4;
  }
}

// ---------------------------------------------------------------------------
// Split xi (fp32) into beta-scaled fp16 hi/lo pair.
// ---------------------------------------------------------------------------
__global__ __launch_bounds__(256)
void split_xi_k(const float* __restrict__ xi, f16* __restrict__ hi,
                f16* __restrict__ lo) {
  const int i = blockIdx.x * 256 + threadIdx.x;  // over float4s: 24576 total
  float4 v = ((const float4*)xi)[i];
  float s[4] = {v.x * BETA, v.y * BETA, v.z * BETA, v.w * BETA};
  f16x4 h4, l4;
#pragma unroll
  for (int j = 0; j < 4; j++) {
    f16 h = (f16)s[j];
    h4[j] = h;
    l4[j] = (f16)(s[j] - (float)h);
  }
  ((f16x4*)hi)[i] = h4;
  ((f16x4*)lo)[i] = l4;
}

// ---------------------------------------------------------------------------
// MFMA flash attention round, full hi/lo precision (fp32-accurate).
// 16x16x32 f16 MFMA only (HW-verified layouts:
//   A[m=lane&15][k=(lane>>4)*8+j], B[n=lane&15][k=(lane>>4)*8+j],
//   C/D col=lane&15 (B-free), row=(lane>>4)*4+reg (A-free)).
// Grid (64 chunks, 16 heads), 256 threads; wave w owns b in [32w, 32w+32).
// Per 32-row iteration: stage k (hi,lo) row-major + value (hi,lo)
// scatter-transposed into LDS (shared by all 4 waves). Scores use 3 split
// terms (kh*xh + kh*xl + kl*xh), 2 K-steps (d=0..31; d=32..47 with lanes
// lq>=2 zeroed in both operands). P split hi/lo in-kernel; PV O^T (dh x b)
// with 3 terms (vh*Ph + vh*Pl + vl*Ph). Unnormalized partials (m,l,O[48]).
// ---------------------------------------------------------------------------
#define FCHUNK 64
#define FROWS (NTOT / FCHUNK)  // 512

__global__ __launch_bounds__(256)
void flash_round(const f16* __restrict__ k_hi, const f16* __restrict__ k_lo,
                 const f16* __restrict__ val_hi, const f16* __restrict__ val_lo,
                 const f16* __restrict__ xi_hi, const f16* __restrict__ xi_lo,
                 float* __restrict__ part_ml, float* __restrict__ part_o) {
  const int h = blockIdx.y, chunk = blockIdx.x;
  const int tid = threadIdx.x, w = tid >> 6, lane = tid & 63;
  const int l15 = lane & 15, lq = lane >> 4;
  const int b0 = w * 32;

  __shared__ __align__(16) f16 krow[2][32][56];  // [hi/lo][n][d], 112B rows
  __shared__ __align__(16) f16 vT[2][48][40];    // [hi/lo][d][n], 80B rows
  __shared__ __align__(16) f16 pHi[4][32][40];   // [wave][b][n]
  __shared__ __align__(16) f16 pLo[4][32][40];

  const f16x8 zf = {};
  // xi B-fragments (persistent): col b = bt*16+l15; K-step s: k = s*32+lq*8+j
  // (s=1 valid only for lanes lq<2 -> d=32..47; others zero).
  f16x8 xqh[2][2], xql[2][2];
#pragma unroll
  for (int bt = 0; bt < 2; bt++) {
    const size_t xoff = (size_t)(b0 + bt * 16 + l15) * DMODEL + h * DH;
    xqh[bt][0] = *(const f16x8*)(xi_hi + xoff + lq * 8);
    xql[bt][0] = *(const f16x8*)(xi_lo + xoff + lq * 8);
    const size_t xo1 = xoff + 32 + (lq & 1) * 8;
    f16x8 th = *(const f16x8*)(xi_hi + xo1);
    f16x8 tl = *(const f16x8*)(xi_lo + xo1);
    xqh[bt][1] = (lq < 2) ? th : zf;
    xql[bt][1] = (lq < 2) ? tl : zf;
  }

  float m[2] = {-1e30f, -1e30f}, lsum[2] = {0.f, 0.f};
  f32x4 O[3][2];
#pragma unroll
  for (int mt = 0; mt < 3; mt++)
#pragma unroll
    for (int bt = 0; bt < 2; bt++)
#pragma unroll
      for (int j = 0; j < 4; j++) O[mt][bt][j] = 0.f;

  const int nbase = chunk * FROWS;
  for (int it = 0; it < FROWS / 32; it++) {
    const int gn0 = nbase + it * 32;
    __syncthreads();  // all waves done reading previous tiles
    // Stage: 384 jobs = {hi,lo} x 32 rows x 6 d-chunks of 8.
    for (int j = tid; j < 384; j += 256) {
      const int tsel = j / 192;
      const int q = j - tsel * 192;
      const int r = q / 6;
      const int d0 = (q - r * 6) * 8;
      const size_t goff = (size_t)(gn0 + r) * DMODEL + h * DH + d0;
      const f16* kp = (tsel ? k_lo : k_hi) + goff;
      const f16* vp = (tsel ? val_lo : val_hi) + goff;
      f16x8 kv = *(const f16x8*)kp;
      f16x8 vv = *(const f16x8*)vp;
      *(f16x8*)&krow[tsel][r][d0] = kv;
#pragma unroll
      for (int jj = 0; jj < 8; jj++) vT[tsel][d0 + jj][r] = vv[jj];
    }
    __syncthreads();

    // Score A-fragments from krow LDS.
    f16x8 akh[2][2], akl[2][2];
#pragma unroll
    for (int nt = 0; nt < 2; nt++) {
      const int row = nt * 16 + l15;
      akh[nt][0] = *(const f16x8*)&krow[0][row][lq * 8];
      akl[nt][0] = *(const f16x8*)&krow[1][row][lq * 8];
      f16x8 t0 = *(const f16x8*)&krow[0][row][32 + (lq & 1) * 8];
      f16x8 t1 = *(const f16x8*)&krow[1][row][32 + (lq & 1) * 8];
      akh[nt][1] = (lq < 2) ? t0 : zf;
      akl[nt][1] = (lq < 2) ? t1 : zf;
    }
    // Scores: 3 split terms x 2 K-steps per (nt, bt).
    f32x4 S[2][2];
#pragma unroll
    for (int nt = 0; nt < 2; nt++)
#pragma unroll
      for (int bt = 0; bt < 2; bt++) {
        f32x4 s = {};
        s = __builtin_amdgcn_mfma_f32_16x16x32_f16(akh[nt][0], xqh[bt][0], s, 0, 0, 0);
        s = __builtin_amdgcn_mfma_f32_16x16x32_f16(akh[nt][1], xqh[bt][1], s, 0, 0, 0);
        s = __builtin_amdgcn_mfma_f32_16x16x32_f16(akh[nt][0], xql[bt][0], s, 0, 0, 0);
        s = __builtin_amdgcn_mfma_f32_16x16x32_f16(akh[nt][1], xql[bt][1], s, 0, 0, 0);
        s = __builtin_amdgcn_mfma_f32_16x16x32_f16(akl[nt][0], xqh[bt][0], s, 0, 0, 0);
        s = __builtin_amdgcn_mfma_f32_16x16x32_f16(akl[nt][1], xqh[bt][1], s, 0, 0, 0);
        S[nt][bt] = s;
      }
    // Online softmax per b (col = bt*16+l15; reduce 8 regs + lanes ^16, ^32).
    float sc[2];
#pragma unroll
    for (int bt = 0; bt < 2; bt++) {
      float mx = S[0][bt][0];
#pragma unroll
      for (int r = 1; r < 4; r++) mx = fmaxf(mx, S[0][bt][r]);
#pragma unroll
      for (int r = 0; r < 4; r++) mx = fmaxf(mx, S[1][bt][r]);
      mx = fmaxf(mx, __shfl_xor(mx, 16));
      mx = fmaxf(mx, __shfl_xor(mx, 32));
      const float mnew = fmaxf(m[bt], mx);
      sc[bt] = __expf(m[bt] - mnew);
      float ps = 0.f;
#pragma unroll
      for (int nt = 0; nt < 2; nt++) {
        f16x4 ph, pl;
#pragma unroll
        for (int r = 0; r < 4; r++) {
          const float p = __expf(S[nt][bt][r] - mnew);
          ps += p;
          const f16 hh = (f16)p;
          ph[r] = hh;
          pl[r] = (f16)(p - (float)hh);
        }
        *(f16x4*)&pHi[w][bt * 16 + l15][nt * 16 + lq * 4] = ph;
        *(f16x4*)&pLo[w][bt * 16 + l15][nt * 16 + lq * 4] = pl;
      }
      ps += __shfl_xor(ps, 16);
      ps += __shfl_xor(ps, 32);
      lsum[bt] = lsum[bt] * sc[bt] + ps;
      m[bt] = mnew;
    }
    __asm__ volatile("s_waitcnt lgkmcnt(0)" ::: "memory");
    // PV fragments. A from vT: row dh = mt*16+l15, k = n = lq*8+j.
    f16x8 avh[3], avl[3];
#pragma unroll
    for (int mt = 0; mt < 3; mt++) {
      avh[mt] = *(const f16x8*)&vT[0][mt * 16 + l15][lq * 8];
      avl[mt] = *(const f16x8*)&vT[1][mt * 16 + l15][lq * 8];
    }
    // B (P): col b = bt*16+l15, k = n = lq*8+j.
    f16x8 pbh[2], pbl[2];
#pragma unroll
    for (int bt = 0; bt < 2; bt++) {
      pbh[bt] = *(const f16x8*)&pHi[w][bt * 16 + l15][lq * 8];
      pbl[bt] = *(const f16x8*)&pLo[w][bt * 16 + l15][lq * 8];
    }
    // Rescale O (col b lane-aligned with sc[bt]) and accumulate 3 terms.
#pragma unroll
    for (int mt = 0; mt < 3; mt++)
#pragma unroll
      for (int bt = 0; bt < 2; bt++) {
#pragma unroll
        for (int j = 0; j < 4; j++) O[mt][bt][j] *= sc[bt];
        f32x4 o = O[mt][bt];
        o = __builtin_amdgcn_mfma_f32_16x16x32_f16(avh[mt], pbh[bt], o, 0, 0, 0);
        o = __builtin_amdgcn_mfma_f32_16x16x32_f16(avh[mt], pbl[bt], o, 0, 0, 0);
        o = __builtin_amdgcn_mfma_f32_16x16x32_f16(avl[mt], pbh[bt], o, 0, 0, 0);
        O[mt][bt] = o;
      }
  }
  // Epilogue: partials. m,l per b from lanes lq==0.
  const int pc = h * FCHUNK + chunk;
  if (lq == 0) {
#pragma unroll
    for (int bt = 0; bt < 2; bt++) {
      float* pm = part_ml + ((size_t)pc * BSZ + b0 + bt * 16 + l15) * 2;
      pm[0] = m[bt];
      pm[1] = lsum[bt];
    }
  }
#pragma unroll
  for (int mt = 0; mt < 3; mt++)
#pragma unroll
    for (int bt = 0; bt < 2; bt++) {
      float* po = part_o + ((size_t)pc * BSZ + b0 + bt * 16 + l15) * 48 +
                  mt * 16 + lq * 4;
      *(f32x4*)po = O[mt][bt];
    }
}

// ---------------------------------------------------------------------------
// Combine 64 chunk-partials per (b,h). Grid = B*H blocks of 64 threads.
// ---------------------------------------------------------------------------
__global__ __launch_bounds__(64)
void hopfield_combine(const float* __restrict__ part_ml,
                      const float* __restrict__ part_o, float* __restrict__ dst) {
  const int bh = blockIdx.x;  // h*128 + b
  const int h = bh >> 7, b = bh & 127;
  const int c = threadIdx.x;
  __shared__ float w[64];
  const float* pm = part_ml + ((size_t)(h * 64 + c) * BSZ + b) * 2;
  const float mp = pm[0];
  const float lp = pm[1];
  float M = mp;
#pragma unroll
  for (int off = 32; off; off >>= 1) M = fmaxf(M, __shfl_xor(M, off));
  const float wp = __expf(mp - M);
  w[c] = wp;
  float L = lp * wp;
#pragma unroll
  for (int off = 32; off; off >>= 1) L += __shfl_xor(L, off);
  __syncthreads();
  if (c < DH) {
    float o = 0.f;
    for (int p = 0; p < 64; p++)
      o += part_o[((size_t)(h * 64 + p) * BSZ + b) * 48 + c] * w[p];
    dst[(size_t)b * DMODEL + h * DH + c] = o / L;
  }
}

// ---------------------------------------------------------------------------
// Top-4 per row with jax tie-breaking (lower index first).
// ---------------------------------------------------------------------------
__global__ __launch_bounds__(256)
void topk_kernel(const float* __restrict__ logits, float* __restrict__ outIdx) {
  const int b = blockIdx.x;
  const int t = threadIdx.x;
  const float* row = logits + (size_t)b * NTOT;
  float v[4] = {-1e30f, -1e30f, -1e30f, -1e30f};
  int id[4] = {0x7fffffff, 0x7fffffff, 0x7fffffff, 0x7fffffff};
  for (int n = t; n < NTOT; n += 256) {
    const float x = row[n];
    if (x > v[3]) {
      v[3] = x; id[3] = n;
#pragma unroll
      for (int s = 3; s > 0; s--) {
        const bool sw = (v[s] > v[s - 1]) || (v[s] == v[s - 1] && id[s] < id[s - 1]);
        if (sw) {
          float tv = v[s]; v[s] = v[s - 1]; v[s - 1] = tv;
          int ti = id[s]; id[s] = id[s - 1]; id[s - 1] = ti;
        }
      }
    }
  }
  __shared__ float sv[256][4];
  __shared__ int si[256][4];
#pragma unroll
  for (int j = 0; j < 4; j++) { sv[t][j] = v[j]; si[t][j] = id[j]; }
  for (int str = 128; str >= 1; str >>= 1) {
    __syncthreads();
    if (t < str) {
      float a[4], c[4];
      int ai[4], ci[4];
#pragma unroll
      for (int j = 0; j < 4; j++) {
        a[j] = sv[t][j]; ai[j] = si[t][j];
        c[j] = sv[t + str][j]; ci[j] = si[t + str][j];
      }
      float rv[4]; int ri[4];
      int p = 0, q = 0;
#pragma unroll
      for (int oo = 0; oo < 4; oo++) {
        const bool ta = (a[p] > c[q]) || (a[p] == c[q] && ai[p] < ci[q]);
        if (ta) { rv[oo] = a[p]; ri[oo] = ai[p]; p++; }
        else    { rv[oo] = c[q]; ri[oo] = ci[q]; q++; }
      }
#pragma unroll
      for (int j = 0; j < 4; j++) { sv[t][j] = rv[j]; si[t][j] = ri[j]; }
    }
  }
  if (t == 0) {
#pragma unroll
    for (int j = 0; j < 4; j++) outIdx[b * 4 + j] = (float)si[0][j];
  }
}

// ---------------------------------------------------------------------------
extern "C" void kernel_launch(void* const* d_in, const int* in_sizes, int n_in,
                              void* d_out, int out_size, void* d_ws, size_t ws_size,
                              hipStream_t stream) {
  const float* qe    = (const float*)d_in[0];
  const float* mb    = (const float*)d_in[1];
  const float* ln_kg = (const float*)d_in[2];
  const float* ln_kb = (const float*)d_in[3];
  const float* ln_qg = (const float*)d_in[4];
  const float* ln_qb = (const float*)d_in[5];
  const float* ln_vg = (const float*)d_in[6];
  const float* ln_vb = (const float*)d_in[7];
  const float* Wq = (const float*)d_in[8];
  const float* bq = (const float*)d_in[9];
  const float* Wk = (const float*)d_in[10];
  const float* bk = (const float*)d_in[11];
  const float* Wv = (const float*)d_in[12];
  const float* bv = (const float*)d_in[13];
  const float* Wo = (const float*)d_in[14];
  const float* bo = (const float*)d_in[15];
  const float* W1 = (const float*)d_in[16];
  const float* b1 = (const float*)d_in[17];
  const float* W2 = (const float*)d_in[18];
  const float* b2 = (const float*)d_in[19];

  float* out = (float*)d_out;  // [0..511] top indices (as float), then logits
  float* logits = out + BSZ * 4;

  float* ws = (float*)d_ws;
  size_t off = 0;
  auto alloc = [&](size_t n) { float* p = ws + off; off += n; return p; };
  const size_t ND2 = (size_t)NTOT * DMODEL / 2;  // one fp16 N*D buffer, in floats
  float* mb_mean = alloc(NTOT);
  float* mb_rstd = alloc(NTOT);
  float* mb_l2i  = alloc(NTOT);
  float* q_mean  = alloc(128);   // reused as rq stats scratch later
  float* q_rstd  = alloc(128);
  float* rq_inv  = alloc(128);
  float* pad_    = alloc(384);   // keep 16B alignment headroom
  f16* k_hi = (f16*)alloc(ND2);  // [N][768] fp16
  f16* k_lo = (f16*)alloc(ND2);
  f16* v_hi = (f16*)alloc(ND2);
  f16* v_lo = (f16*)alloc(ND2);
  float* part_ml = alloc((size_t)NHEAD * FCHUNK * BSZ * 2);
  float* part_o  = alloc((size_t)NHEAD * FCHUNK * BSZ * 48);
  float* xi   = alloc((size_t)BSZ * DMODEL);
  float* conv = alloc((size_t)BSZ * DMODEL);
  float* comb = alloc((size_t)BSZ * DMODEL);  // also reused for rq
  float* h1   = alloc((size_t)BSZ * DMODEL);
  f16* xi_hi = (f16*)alloc((size_t)BSZ * DMODEL / 2);
  f16* xi_lo = (f16*)alloc((size_t)BSZ * DMODEL / 2);
  (void)ws_size; (void)in_sizes; (void)n_in; (void)out_size; (void)pad_;

  // 1. stats
  row_stats<<<NTOT / 4, 256, 0, stream>>>(mb, NTOT, mb_mean, mb_rstd, mb_l2i);
  row_stats<<<BSZ / 4, 256, 0, stream>>>(qe, BSZ, q_mean, q_rstd, nullptr);

  // 2. projections: k,v -> fp16 hi/lo pairs; q (xi) fp32
  ln_gemm_split<<<dim3(DMODEL / 64, NTOT / 64), 256, 0, stream>>>(
      mb, mb_mean, mb_rstd, ln_kg, ln_kb, Wk, bk, k_hi, k_lo);
  ln_gemm_split<<<dim3(DMODEL / 64, NTOT / 64), 256, 0, stream>>>(
      mb, mb_mean, mb_rstd, ln_vg, ln_vb, Wv, bv, v_hi, v_lo);
  ln_gemm_f32<<<dim3(DMODEL / 64, BSZ / 64), 256, 0, stream>>>(
      qe, q_mean, q_rstd, ln_qg, ln_qb, Wq, bq, xi);

  // 3. Hopfield: 5 updates (value = k), then readout (value = v)
  for (int r = 0; r < 6; r++) {
    const f16* valHi = (r == 5) ? v_hi : k_hi;
    const f16* valLo = (r == 5) ? v_lo : k_lo;
    float* dst = (r == 5) ? conv : xi;
    split_xi_k<<<96, 256, 0, stream>>>(xi, xi_hi, xi_lo);
    flash_round<<<dim3(FCHUNK, NHEAD), 256, 0, stream>>>(
        k_hi, k_lo, valHi, valLo, xi_hi, xi_lo, part_ml, part_o);
    hopfield_combine<<<BSZ * NHEAD, 64, 0, stream>>>(part_ml, part_o, dst);
  }

  // 4. readout MLP: comb = qe + conv@Wo^T+bo; h1 = relu(comb@W1^T+b1);
  //    rq = h1@W2^T+b2 (written into comb, which is dead by then)
  gemm_bias<<<dim3(DMODEL / 64, BSZ / 64), 256, 0, stream>>>(conv, Wo, bo, qe, comb, 0);
  gemm_bias<<<dim3(DMODEL / 64, BSZ / 64), 256, 0, stream>>>(comb, W1, b1, nullptr, h1, 1);
  float* rq = conv;  // conv dead after comb computed; reuse for rq
  gemm_bias<<<dim3(DMODEL / 64, BSZ / 64), 256, 0, stream>>>(h1, W2, b2, nullptr, rq, 0);

  // 5. cosine logits
  row_stats<<<BSZ / 4, 256, 0, stream>>>(rq, BSZ, q_mean, q_rstd, rq_inv);
  logits_gemm<<<dim3(NTOT / 64, BSZ / 64), 256, 0, stream>>>(rq, mb, rq_inv, mb_l2i, logits);

  // 6. top-4 indices
  topk_kernel<<<BSZ, 256, 0, stream>>>(logits, out);
}

// Round 5
// 1474.200 us; speedup vs baseline: 2.9285x; 1.5352x over previous
//
#include <hip/hip_runtime.h>
#include <math.h>

#define NTOT 32768
#define DMODEL 768
#define BSZ 128
#define NHEAD 16
#define DH 48
#define BETA 0.25f

typedef _Float16 f16;
typedef f16 f16x8 __attribute__((ext_vector_type(8)));
typedef f16 f16x4 __attribute__((ext_vector_type(4)));
typedef float f32x4 __attribute__((ext_vector_type(4)));

// ---------------------------------------------------------------------------
// Row stats: mean, rstd (LN, biased var, eps=1e-5), optional l2inv of raw row.
// ---------------------------------------------------------------------------
__global__ __launch_bounds__(256)
void row_stats(const float* __restrict__ X, int M, float* __restrict__ mean,
               float* __restrict__ rstd, float* __restrict__ l2inv) {
  const int row = blockIdx.x * 4 + (threadIdx.x >> 6);
  const int lane = threadIdx.x & 63;
  if (row >= M) return;
  const float* x = X + (size_t)row * DMODEL;
  float s = 0.f, s2 = 0.f;
  for (int i = lane; i < DMODEL; i += 64) {
    float v = x[i];
    s += v; s2 += v * v;
  }
#pragma unroll
  for (int off = 32; off; off >>= 1) {
    s  += __shfl_xor(s, off);
    s2 += __shfl_xor(s2, off);
  }
  if (lane == 0) {
    float mu = s * (1.f / DMODEL);
    float var = s2 * (1.f / DMODEL) - mu * mu;
    mean[row] = mu;
    rstd[row] = rsqrtf(var + 1e-5f);
    if (l2inv) l2inv[row] = 1.f / fmaxf(sqrtf(s2), 1e-12f);
  }
}

// ---------------------------------------------------------------------------
// prep_w: combined W' (o<768: g_k*Wk rows; o>=768: g_v*Wv rows), scaled x16,
// split fp16 hi/lo; biasc[o] = bias[o] + sum_d bln[d]*W[o,d].
// Grid 384 x 256 (one wave per o-row).
// ---------------------------------------------------------------------------
__global__ __launch_bounds__(256)
void prep_w(const float* __restrict__ Wk, const float* __restrict__ bk,
            const float* __restrict__ gk, const float* __restrict__ blnk,
            const float* __restrict__ Wv, const float* __restrict__ bv,
            const float* __restrict__ gv, const float* __restrict__ blnv,
            f16* __restrict__ Wc_hi, f16* __restrict__ Wc_lo,
            float* __restrict__ biasc) {
  const int o = blockIdx.x * 4 + (threadIdx.x >> 6);  // 0..1535
  const int lane = threadIdx.x & 63;
  const bool isK = o < DMODEL;
  const float* W = isK ? (Wk + (size_t)o * DMODEL)
                       : (Wv + (size_t)(o - DMODEL) * DMODEL);
  const float* g   = isK ? gk : gv;
  const float* bln = isK ? blnk : blnv;
  float bacc = 0.f;
  for (int d = lane * 4; d < DMODEL; d += 256) {
    const float4 wv = *(const float4*)(W + d);
    const float4 g4 = *(const float4*)(g + d);
    const float4 b4 = *(const float4*)(bln + d);
    bacc += wv.x * b4.x + wv.y * b4.y + wv.z * b4.z + wv.w * b4.w;
    const float sv[4] = {wv.x * g4.x * 16.f, wv.y * g4.y * 16.f,
                         wv.z * g4.z * 16.f, wv.w * g4.w * 16.f};
    f16x4 h4, l4;
#pragma unroll
    for (int j = 0; j < 4; j++) {
      const f16 h = (f16)sv[j];
      h4[j] = h;
      l4[j] = (f16)(sv[j] - (float)h);
    }
    *(f16x4*)(Wc_hi + (size_t)o * DMODEL + d) = h4;
    *(f16x4*)(Wc_lo + (size_t)o * DMODEL + d) = l4;
  }
#pragma unroll
  for (int off = 32; off; off >>= 1) bacc += __shfl_xor(bacc, off);
  if (lane == 0) biasc[o] = (isK ? bk[o] : bv[o - DMODEL]) + bacc;
}

// ---------------------------------------------------------------------------
// Fused dual projection GEMM via 16x16x32 f16 MFMA, 3-term hi/lo split
// (fp32-equivalent). C[m, o] = nh[m] . Wc'[o] / 16 + biasc[o], written as
// fp16 hi/lo into k or v buffers (o<768 -> k, else v).
// Tiles: 128 (m) x 128 (o), BK=32; 256 threads = 4 waves in 2x2; each wave
// 64x64. W' is the MFMA A-operand (C/D row = o), nh is B (C/D col = m).
// Layouts (HW-verified): A/B [free=lane&15][k=(lane>>4)*8+j];
// D col=lane&15 (B-free=m), row=(lane>>4)*4+reg (A-free=o).
// ---------------------------------------------------------------------------
__global__ __launch_bounds__(256)
void proj_dual_mfma(const float* __restrict__ mb, const float* __restrict__ mean,
                    const float* __restrict__ rstd,
                    const f16* __restrict__ Wc_hi, const f16* __restrict__ Wc_lo,
                    const float* __restrict__ biasc,
                    f16* __restrict__ k_hi, f16* __restrict__ k_lo,
                    f16* __restrict__ v_hi, f16* __restrict__ v_lo) {
  __shared__ __align__(16) f16 As[2][128][40];  // [hi/lo][m][k] stride 80B
  __shared__ __align__(16) f16 Bs[2][128][40];  // [hi/lo][o][k]
  const int t = threadIdx.x;
  const int n0 = blockIdx.x * 128;  // combined o base (0..1408)
  const int m0 = blockIdx.y * 128;
  const int w = t >> 6, lane = t & 63;
  const int l15 = lane & 15, lq = lane >> 4;
  const int wm = w >> 1, wn = w & 1;
  const int sr = t >> 1, sh = t & 1;  // staging: row 0..127, k-half 0/1
  const float mu = mean[m0 + sr];
  const float rs = rstd[m0 + sr];

  f32x4 acc[4][4];  // [fo][fm]
#pragma unroll
  for (int a = 0; a < 4; a++)
#pragma unroll
    for (int b = 0; b < 4; b++)
#pragma unroll
      for (int r = 0; r < 4; r++) acc[a][b][r] = 0.f;

  for (int k0 = 0; k0 < DMODEL; k0 += 32) {
    __syncthreads();
    // --- A staging: load 16 fp32, normalize, split hi/lo ---
    {
      const float* ap = mb + (size_t)(m0 + sr) * DMODEL + k0 + sh * 16;
      float x[16];
#pragma unroll
      for (int c = 0; c < 4; c++) {
        const float4 v4 = *(const float4*)(ap + c * 4);
        x[c * 4 + 0] = v4.x; x[c * 4 + 1] = v4.y;
        x[c * 4 + 2] = v4.z; x[c * 4 + 3] = v4.w;
      }
      f16x8 h0, h1, l0, l1;
#pragma unroll
      for (int j = 0; j < 8; j++) {
        const float s = (x[j] - mu) * rs;
        const f16 h = (f16)s;
        h0[j] = h; l0[j] = (f16)(s - (float)h);
      }
#pragma unroll
      for (int j = 0; j < 8; j++) {
        const float s = (x[8 + j] - mu) * rs;
        const f16 h = (f16)s;
        h1[j] = h; l1[j] = (f16)(s - (float)h);
      }
      *(f16x8*)&As[0][sr][sh * 16] = h0;
      *(f16x8*)&As[0][sr][sh * 16 + 8] = h1;
      *(f16x8*)&As[1][sr][sh * 16] = l0;
      *(f16x8*)&As[1][sr][sh * 16 + 8] = l1;
    }
    // --- B staging: copy prepared fp16 hi/lo ---
    {
      const size_t boff = (size_t)(n0 + sr) * DMODEL + k0 + sh * 16;
      f16x8 bh0 = *(const f16x8*)(Wc_hi + boff);
      f16x8 bh1 = *(const f16x8*)(Wc_hi + boff + 8);
      f16x8 bl0 = *(const f16x8*)(Wc_lo + boff);
      f16x8 bl1 = *(const f16x8*)(Wc_lo + boff + 8);
      *(f16x8*)&Bs[0][sr][sh * 16] = bh0;
      *(f16x8*)&Bs[0][sr][sh * 16 + 8] = bh1;
      *(f16x8*)&Bs[1][sr][sh * 16] = bl0;
      *(f16x8*)&Bs[1][sr][sh * 16 + 8] = bl1;
    }
    __syncthreads();
    // --- fragments ---
    f16x8 nhh[4], nhl[4];  // nh (B operand), free = m
#pragma unroll
    for (int fm = 0; fm < 4; fm++) {
      const int row = wm * 64 + fm * 16 + l15;
      nhh[fm] = *(const f16x8*)&As[0][row][lq * 8];
      nhl[fm] = *(const f16x8*)&As[1][row][lq * 8];
    }
    f16x8 wh[4], wl[4];  // W' (A operand), free = o
#pragma unroll
    for (int fo = 0; fo < 4; fo++) {
      const int row = wn * 64 + fo * 16 + l15;
      wh[fo] = *(const f16x8*)&Bs[0][row][lq * 8];
      wl[fo] = *(const f16x8*)&Bs[1][row][lq * 8];
    }
    // --- 48 MFMAs: 3 split terms per (fo, fm) ---
#pragma unroll
    for (int fo = 0; fo < 4; fo++)
#pragma unroll
      for (int fm = 0; fm < 4; fm++) {
        f32x4 a = acc[fo][fm];
        a = __builtin_amdgcn_mfma_f32_16x16x32_f16(wh[fo], nhh[fm], a, 0, 0, 0);
        a = __builtin_amdgcn_mfma_f32_16x16x32_f16(wh[fo], nhl[fm], a, 0, 0, 0);
        a = __builtin_amdgcn_mfma_f32_16x16x32_f16(wl[fo], nhh[fm], a, 0, 0, 0);
        acc[fo][fm] = a;
      }
  }
  // --- epilogue: /16, +bias, split hi/lo, 8B stores ---
  const int oc = n0 + wn * 64;
  const bool isK = oc < DMODEL;
  f16* oh = isK ? k_hi : v_hi;
  f16* ol = isK ? k_lo : v_lo;
  const int obase = (isK ? oc : oc - DMODEL) + lq * 4;
#pragma unroll
  for (int fo = 0; fo < 4; fo++) {
    const float4 bb = *(const float4*)(biasc + oc + fo * 16 + lq * 4);
    const float bbv[4] = {bb.x, bb.y, bb.z, bb.w};
    const int o = obase + fo * 16;
#pragma unroll
    for (int fm = 0; fm < 4; fm++) {
      const size_t moff = (size_t)(m0 + wm * 64 + fm * 16 + l15) * DMODEL + o;
      f16x4 h4, l4;
#pragma unroll
      for (int r = 0; r < 4; r++) {
        const float v = acc[fo][fm][r] * 0.0625f + bbv[r];
        const f16 h = (f16)v;
        h4[r] = h;
        l4[r] = (f16)(v - (float)h);
      }
      *(f16x4*)(oh + moff) = h4;
      *(f16x4*)(ol + moff) = l4;
    }
  }
}

// ---------------------------------------------------------------------------
// LN-fused GEMM, fp32 output (for q projection).
// ---------------------------------------------------------------------------
__global__ __launch_bounds__(256)
void ln_gemm_f32(const float* __restrict__ A, const float* __restrict__ mean,
                 const float* __restrict__ rstd, const float* __restrict__ g,
                 const float* __restrict__ bln, const float* __restrict__ W,
                 const float* __restrict__ bias, float* __restrict__ out) {
  __shared__ float As[16][68];
  __shared__ float Ws[16][68];
  const int t = threadIdx.x;
  const int m0 = blockIdx.y << 6, n0 = blockIdx.x << 6;
  const int tm = t >> 4, tn = t & 15;
  const int lr = t >> 2;
  const int lk = (t & 3) << 2;
  const float muL = mean[m0 + lr];
  const float rsL = rstd[m0 + lr];
  float acc[4][4] = {};
  for (int k0 = 0; k0 < DMODEL; k0 += 16) {
    float4 a4 = *(const float4*)(A + (size_t)(m0 + lr) * DMODEL + k0 + lk);
    float4 g4 = *(const float4*)(g + k0 + lk);
    float4 b4 = *(const float4*)(bln + k0 + lk);
    As[lk + 0][lr] = (a4.x - muL) * rsL * g4.x + b4.x;
    As[lk + 1][lr] = (a4.y - muL) * rsL * g4.y + b4.y;
    As[lk + 2][lr] = (a4.z - muL) * rsL * g4.z + b4.z;
    As[lk + 3][lr] = (a4.w - muL) * rsL * g4.w + b4.w;
    float4 w4 = *(const float4*)(W + (size_t)(n0 + lr) * DMODEL + k0 + lk);
    Ws[lk + 0][lr] = w4.x;
    Ws[lk + 1][lr] = w4.y;
    Ws[lk + 2][lr] = w4.z;
    Ws[lk + 3][lr] = w4.w;
    __syncthreads();
#pragma unroll
    for (int kk = 0; kk < 16; kk++) {
      const float4 av = *(const float4*)(&As[kk][tm * 4]);
      const float4 bv = *(const float4*)(&Ws[kk][tn * 4]);
      const float a[4] = {av.x, av.y, av.z, av.w};
      const float b[4] = {bv.x, bv.y, bv.z, bv.w};
#pragma unroll
      for (int i = 0; i < 4; i++)
#pragma unroll
        for (int j = 0; j < 4; j++) acc[i][j] += a[i] * b[j];
    }
    __syncthreads();
  }
  const float4 bia = *(const float4*)(bias + n0 + tn * 4);
  const float bb[4] = {bia.x, bia.y, bia.z, bia.w};
#pragma unroll
  for (int i = 0; i < 4; i++) {
    const int m = m0 + tm * 4 + i;
    float4 o4;
    o4.x = acc[i][0] + bb[0];
    o4.y = acc[i][1] + bb[1];
    o4.z = acc[i][2] + bb[2];
    o4.w = acc[i][3] + bb[3];
    *(float4*)(out + (size_t)m * DMODEL + n0 + tn * 4) = o4;
  }
}

// ---------------------------------------------------------------------------
// Plain small GEMM: out = act(A @ W^T + bias [+ add])
// ---------------------------------------------------------------------------
__global__ __launch_bounds__(256)
void gemm_bias(const float* __restrict__ A, const float* __restrict__ W,
               const float* __restrict__ bias, const float* __restrict__ add,
               float* __restrict__ out, int relu) {
  __shared__ float As[16][68];
  __shared__ float Ws[16][68];
  const int t = threadIdx.x;
  const int m0 = blockIdx.y << 6, n0 = blockIdx.x << 6;
  const int tm = t >> 4, tn = t & 15;
  const int lr = t >> 2;
  const int lk = (t & 3) << 2;
  float acc[4][4] = {};
  for (int k0 = 0; k0 < DMODEL; k0 += 16) {
    float4 a4 = *(const float4*)(A + (size_t)(m0 + lr) * DMODEL + k0 + lk);
    As[lk + 0][lr] = a4.x;
    As[lk + 1][lr] = a4.y;
    As[lk + 2][lr] = a4.z;
    As[lk + 3][lr] = a4.w;
    float4 w4 = *(const float4*)(W + (size_t)(n0 + lr) * DMODEL + k0 + lk);
    Ws[lk + 0][lr] = w4.x;
    Ws[lk + 1][lr] = w4.y;
    Ws[lk + 2][lr] = w4.z;
    Ws[lk + 3][lr] = w4.w;
    __syncthreads();
#pragma unroll
    for (int kk = 0; kk < 16; kk++) {
      const float4 av = *(const float4*)(&As[kk][tm * 4]);
      const float4 bv = *(const float4*)(&Ws[kk][tn * 4]);
      const float a[4] = {av.x, av.y, av.z, av.w};
      const float b[4] = {bv.x, bv.y, bv.z, bv.w};
#pragma unroll
      for (int i = 0; i < 4; i++)
#pragma unroll
        for (int j = 0; j < 4; j++) acc[i][j] += a[i] * b[j];
    }
    __syncthreads();
  }
  const float4 bia = *(const float4*)(bias + n0 + tn * 4);
  const float bb[4] = {bia.x, bia.y, bia.z, bia.w};
#pragma unroll
  for (int i = 0; i < 4; i++) {
    const int m = m0 + tm * 4 + i;
    float v[4];
#pragma unroll
    for (int j = 0; j < 4; j++) v[j] = acc[i][j] + bb[j];
    if (add) {
      const float4 a4 = *(const float4*)(add + (size_t)m * DMODEL + n0 + tn * 4);
      v[0] += a4.x; v[1] += a4.y; v[2] += a4.z; v[3] += a4.w;
    }
    if (relu) {
#pragma unroll
      for (int j = 0; j < 4; j++) v[j] = fmaxf(v[j], 0.f);
    }
    float4 o4 = {v[0], v[1], v[2], v[3]};
    *(float4*)(out + (size_t)m * DMODEL + n0 + tn * 4) = o4;
  }
}

// ---------------------------------------------------------------------------
// logits[m, n] = 20 * ainv[m] * binv[n] * (rq[m] . mb[n])
// ---------------------------------------------------------------------------
__global__ __launch_bounds__(256)
void logits_gemm(const float* __restrict__ A, const float* __restrict__ Bm,
                 const float* __restrict__ ainv, const float* __restrict__ binv,
                 float* __restrict__ out) {
  __shared__ float As[16][68];
  __shared__ float Ws[16][68];
  const int t = threadIdx.x;
  const int m0 = blockIdx.y << 6, n0 = blockIdx.x << 6;
  const int tm = t >> 4, tn = t & 15;
  const int lr = t >> 2;
  const int lk = (t & 3) << 2;
  float acc[4][4] = {};
  for (int k0 = 0; k0 < DMODEL; k0 += 16) {
    float4 a4 = *(const float4*)(A + (size_t)(m0 + lr) * DMODEL + k0 + lk);
    As[lk + 0][lr] = a4.x;
    As[lk + 1][lr] = a4.y;
    As[lk + 2][lr] = a4.z;
    As[lk + 3][lr] = a4.w;
    float4 w4 = *(const float4*)(Bm + (size_t)(n0 + lr) * DMODEL + k0 + lk);
    Ws[lk + 0][lr] = w4.x;
    Ws[lk + 1][lr] = w4.y;
    Ws[lk + 2][lr] = w4.z;
    Ws[lk + 3][lr] = w4.w;
    __syncthreads();
#pragma unroll
    for (int kk = 0; kk < 16; kk++) {
      const float4 av = *(const float4*)(&As[kk][tm * 4]);
      const float4 bv = *(const float4*)(&Ws[kk][tn * 4]);
      const float a[4] = {av.x, av.y, av.z, av.w};
      const float b[4] = {bv.x, bv.y, bv.z, bv.w};
#pragma unroll
      for (int i = 0; i < 4; i++)
#pragma unroll
        for (int j = 0; j < 4; j++) acc[i][j] += a[i] * b[j];
    }
    __syncthreads();
  }
  const float4 bi4 = *(const float4*)(binv + n0 + tn * 4);
  const float bi[4] = {bi4.x, bi4.y, bi4.z, bi4.w};
#pragma unroll
  for (int i = 0; i < 4; i++) {
    const int m = m0 + tm * 4 + i;
    const float sa = 20.f * ainv[m];
    float4 o4;
    o4.x = acc[i][0] * sa * bi[0];
    o4.y = acc[i][1] * sa * bi[1];
    o4.z = acc[i][2] * sa * bi[2];
    o4.w = acc[i][3] * sa * bi[3];
    *(float4*)(out + (size_t)m * NTOT + n0 + tn * 4) = o4;
  }
}

// ---------------------------------------------------------------------------
// Split xi (fp32) into beta-scaled fp16 hi/lo pair.
// ---------------------------------------------------------------------------
__global__ __launch_bounds__(256)
void split_xi_k(const float* __restrict__ xi, f16* __restrict__ hi,
                f16* __restrict__ lo) {
  const int i = blockIdx.x * 256 + threadIdx.x;  // over float4s: 24576 total
  float4 v = ((const float4*)xi)[i];
  float s[4] = {v.x * BETA, v.y * BETA, v.z * BETA, v.w * BETA};
  f16x4 h4, l4;
#pragma unroll
  for (int j = 0; j < 4; j++) {
    f16 h = (f16)s[j];
    h4[j] = h;
    l4[j] = (f16)(s[j] - (float)h);
  }
  ((f16x4*)hi)[i] = h4;
  ((f16x4*)lo)[i] = l4;
}

// ---------------------------------------------------------------------------
// MFMA flash attention round, full hi/lo precision (fp32-accurate).
// (unchanged from Round 4 — passed at absmax floor)
// ---------------------------------------------------------------------------
#define FCHUNK 64
#define FROWS (NTOT / FCHUNK)  // 512

__global__ __launch_bounds__(256)
void flash_round(const f16* __restrict__ k_hi, const f16* __restrict__ k_lo,
                 const f16* __restrict__ val_hi, const f16* __restrict__ val_lo,
                 const f16* __restrict__ xi_hi, const f16* __restrict__ xi_lo,
                 float* __restrict__ part_ml, float* __restrict__ part_o) {
  const int h = blockIdx.y, chunk = blockIdx.x;
  const int tid = threadIdx.x, w = tid >> 6, lane = tid & 63;
  const int l15 = lane & 15, lq = lane >> 4;
  const int b0 = w * 32;

  __shared__ __align__(16) f16 krow[2][32][56];
  __shared__ __align__(16) f16 vT[2][48][40];
  __shared__ __align__(16) f16 pHi[4][32][40];
  __shared__ __align__(16) f16 pLo[4][32][40];

  const f16x8 zf = {};
  f16x8 xqh[2][2], xql[2][2];
#pragma unroll
  for (int bt = 0; bt < 2; bt++) {
    const size_t xoff = (size_t)(b0 + bt * 16 + l15) * DMODEL + h * DH;
    xqh[bt][0] = *(const f16x8*)(xi_hi + xoff + lq * 8);
    xql[bt][0] = *(const f16x8*)(xi_lo + xoff + lq * 8);
    const size_t xo1 = xoff + 32 + (lq & 1) * 8;
    f16x8 th = *(const f16x8*)(xi_hi + xo1);
    f16x8 tl = *(const f16x8*)(xi_lo + xo1);
    xqh[bt][1] = (lq < 2) ? th : zf;
    xql[bt][1] = (lq < 2) ? tl : zf;
  }

  float m[2] = {-1e30f, -1e30f}, lsum[2] = {0.f, 0.f};
  f32x4 O[3][2];
#pragma unroll
  for (int mt = 0; mt < 3; mt++)
#pragma unroll
    for (int bt = 0; bt < 2; bt++)
#pragma unroll
      for (int j = 0; j < 4; j++) O[mt][bt][j] = 0.f;

  const int nbase = chunk * FROWS;
  for (int it = 0; it < FROWS / 32; it++) {
    const int gn0 = nbase + it * 32;
    __syncthreads();
    for (int j = tid; j < 384; j += 256) {
      const int tsel = j / 192;
      const int q = j - tsel * 192;
      const int r = q / 6;
      const int d0 = (q - r * 6) * 8;
      const size_t goff = (size_t)(gn0 + r) * DMODEL + h * DH + d0;
      const f16* kp = (tsel ? k_lo : k_hi) + goff;
      const f16* vp = (tsel ? val_lo : val_hi) + goff;
      f16x8 kv = *(const f16x8*)kp;
      f16x8 vv = *(const f16x8*)vp;
      *(f16x8*)&krow[tsel][r][d0] = kv;
#pragma unroll
      for (int jj = 0; jj < 8; jj++) vT[tsel][d0 + jj][r] = vv[jj];
    }
    __syncthreads();

    f16x8 akh[2][2], akl[2][2];
#pragma unroll
    for (int nt = 0; nt < 2; nt++) {
      const int row = nt * 16 + l15;
      akh[nt][0] = *(const f16x8*)&krow[0][row][lq * 8];
      akl[nt][0] = *(const f16x8*)&krow[1][row][lq * 8];
      f16x8 t0 = *(const f16x8*)&krow[0][row][32 + (lq & 1) * 8];
      f16x8 t1 = *(const f16x8*)&krow[1][row][32 + (lq & 1) * 8];
      akh[nt][1] = (lq < 2) ? t0 : zf;
      akl[nt][1] = (lq < 2) ? t1 : zf;
    }
    f32x4 S[2][2];
#pragma unroll
    for (int nt = 0; nt < 2; nt++)
#pragma unroll
      for (int bt = 0; bt < 2; bt++) {
        f32x4 s = {};
        s = __builtin_amdgcn_mfma_f32_16x16x32_f16(akh[nt][0], xqh[bt][0], s, 0, 0, 0);
        s = __builtin_amdgcn_mfma_f32_16x16x32_f16(akh[nt][1], xqh[bt][1], s, 0, 0, 0);
        s = __builtin_amdgcn_mfma_f32_16x16x32_f16(akh[nt][0], xql[bt][0], s, 0, 0, 0);
        s = __builtin_amdgcn_mfma_f32_16x16x32_f16(akh[nt][1], xql[bt][1], s, 0, 0, 0);
        s = __builtin_amdgcn_mfma_f32_16x16x32_f16(akl[nt][0], xqh[bt][0], s, 0, 0, 0);
        s = __builtin_amdgcn_mfma_f32_16x16x32_f16(akl[nt][1], xqh[bt][1], s, 0, 0, 0);
        S[nt][bt] = s;
      }
    float sc[2];
#pragma unroll
    for (int bt = 0; bt < 2; bt++) {
      float mx = S[0][bt][0];
#pragma unroll
      for (int r = 1; r < 4; r++) mx = fmaxf(mx, S[0][bt][r]);
#pragma unroll
      for (int r = 0; r < 4; r++) mx = fmaxf(mx, S[1][bt][r]);
      mx = fmaxf(mx, __shfl_xor(mx, 16));
      mx = fmaxf(mx, __shfl_xor(mx, 32));
      const float mnew = fmaxf(m[bt], mx);
      sc[bt] = __expf(m[bt] - mnew);
      float ps = 0.f;
#pragma unroll
      for (int nt = 0; nt < 2; nt++) {
        f16x4 ph, pl;
#pragma unroll
        for (int r = 0; r < 4; r++) {
          const float p = __expf(S[nt][bt][r] - mnew);
          ps += p;
          const f16 hh = (f16)p;
          ph[r] = hh;
          pl[r] = (f16)(p - (float)hh);
        }
        *(f16x4*)&pHi[w][bt * 16 + l15][nt * 16 + lq * 4] = ph;
        *(f16x4*)&pLo[w][bt * 16 + l15][nt * 16 + lq * 4] = pl;
      }
      ps += __shfl_xor(ps, 16);
      ps += __shfl_xor(ps, 32);
      lsum[bt] = lsum[bt] * sc[bt] + ps;
      m[bt] = mnew;
    }
    __asm__ volatile("s_waitcnt lgkmcnt(0)" ::: "memory");
    f16x8 avh[3], avl[3];
#pragma unroll
    for (int mt = 0; mt < 3; mt++) {
      avh[mt] = *(const f16x8*)&vT[0][mt * 16 + l15][lq * 8];
      avl[mt] = *(const f16x8*)&vT[1][mt * 16 + l15][lq * 8];
    }
    f16x8 pbh[2], pbl[2];
#pragma unroll
    for (int bt = 0; bt < 2; bt++) {
      pbh[bt] = *(const f16x8*)&pHi[w][bt * 16 + l15][lq * 8];
      pbl[bt] = *(const f16x8*)&pLo[w][bt * 16 + l15][lq * 8];
    }
#pragma unroll
    for (int mt = 0; mt < 3; mt++)
#pragma unroll
      for (int bt = 0; bt < 2; bt++) {
#pragma unroll
        for (int j = 0; j < 4; j++) O[mt][bt][j] *= sc[bt];
        f32x4 o = O[mt][bt];
        o = __builtin_amdgcn_mfma_f32_16x16x32_f16(avh[mt], pbh[bt], o, 0, 0, 0);
        o = __builtin_amdgcn_mfma_f32_16x16x32_f16(avh[mt], pbl[bt], o, 0, 0, 0);
        o = __builtin_amdgcn_mfma_f32_16x16x32_f16(avl[mt], pbh[bt], o, 0, 0, 0);
        O[mt][bt] = o;
      }
  }
  const int pc = h * FCHUNK + chunk;
  if (lq == 0) {
#pragma unroll
    for (int bt = 0; bt < 2; bt++) {
      float* pm = part_ml + ((size_t)pc * BSZ + b0 + bt * 16 + l15) * 2;
      pm[0] = m[bt];
      pm[1] = lsum[bt];
    }
  }
#pragma unroll
  for (int mt = 0; mt < 3; mt++)
#pragma unroll
    for (int bt = 0; bt < 2; bt++) {
      float* po = part_o + ((size_t)pc * BSZ + b0 + bt * 16 + l15) * 48 +
                  mt * 16 + lq * 4;
      *(f32x4*)po = O[mt][bt];
    }
}

// ---------------------------------------------------------------------------
// Combine 64 chunk-partials per (b,h). Grid = B*H blocks of 64 threads.
// ---------------------------------------------------------------------------
__global__ __launch_bounds__(64)
void hopfield_combine(const float* __restrict__ part_ml,
                      const float* __restrict__ part_o, float* __restrict__ dst) {
  const int bh = blockIdx.x;  // h*128 + b
  const int h = bh >> 7, b = bh & 127;
  const int c = threadIdx.x;
  __shared__ float w[64];
  const float* pm = part_ml + ((size_t)(h * 64 + c) * BSZ + b) * 2;
  const float mp = pm[0];
  const float lp = pm[1];
  float M = mp;
#pragma unroll
  for (int off = 32; off; off >>= 1) M = fmaxf(M, __shfl_xor(M, off));
  const float wp = __expf(mp - M);
  w[c] = wp;
  float L = lp * wp;
#pragma unroll
  for (int off = 32; off; off >>= 1) L += __shfl_xor(L, off);
  __syncthreads();
  if (c < DH) {
    float o = 0.f;
    for (int p = 0; p < 64; p++)
      o += part_o[((size_t)(h * 64 + p) * BSZ + b) * 48 + c] * w[p];
    dst[(size_t)b * DMODEL + h * DH + c] = o / L;
  }
}

// ---------------------------------------------------------------------------
// Top-4 per row with jax tie-breaking (lower index first).
// ---------------------------------------------------------------------------
__global__ __launch_bounds__(256)
void topk_kernel(const float* __restrict__ logits, float* __restrict__ outIdx) {
  const int b = blockIdx.x;
  const int t = threadIdx.x;
  const float* row = logits + (size_t)b * NTOT;
  float v[4] = {-1e30f, -1e30f, -1e30f, -1e30f};
  int id[4] = {0x7fffffff, 0x7fffffff, 0x7fffffff, 0x7fffffff};
  for (int n = t; n < NTOT; n += 256) {
    const float x = row[n];
    if (x > v[3]) {
      v[3] = x; id[3] = n;
#pragma unroll
      for (int s = 3; s > 0; s--) {
        const bool sw = (v[s] > v[s - 1]) || (v[s] == v[s - 1] && id[s] < id[s - 1]);
        if (sw) {
          float tv = v[s]; v[s] = v[s - 1]; v[s - 1] = tv;
          int ti = id[s]; id[s] = id[s - 1]; id[s - 1] = ti;
        }
      }
    }
  }
  __shared__ float sv[256][4];
  __shared__ int si[256][4];
#pragma unroll
  for (int j = 0; j < 4; j++) { sv[t][j] = v[j]; si[t][j] = id[j]; }
  for (int str = 128; str >= 1; str >>= 1) {
    __syncthreads();
    if (t < str) {
      float a[4], c[4];
      int ai[4], ci[4];
#pragma unroll
      for (int j = 0; j < 4; j++) {
        a[j] = sv[t][j]; ai[j] = si[t][j];
        c[j] = sv[t + str][j]; ci[j] = si[t + str][j];
      }
      float rv[4]; int ri[4];
      int p = 0, q = 0;
#pragma unroll
      for (int oo = 0; oo < 4; oo++) {
        const bool ta = (a[p] > c[q]) || (a[p] == c[q] && ai[p] < ci[q]);
        if (ta) { rv[oo] = a[p]; ri[oo] = ai[p]; p++; }
        else    { rv[oo] = c[q]; ri[oo] = ci[q]; q++; }
      }
#pragma unroll
      for (int j = 0; j < 4; j++) { sv[t][j] = rv[j]; si[t][j] = ri[j]; }
    }
  }
  if (t == 0) {
#pragma unroll
    for (int j = 0; j < 4; j++) outIdx[b * 4 + j] = (float)si[0][j];
  }
}

// ---------------------------------------------------------------------------
extern "C" void kernel_launch(void* const* d_in, const int* in_sizes, int n_in,
                              void* d_out, int out_size, void* d_ws, size_t ws_size,
                              hipStream_t stream) {
  const float* qe    = (const float*)d_in[0];
  const float* mb    = (const float*)d_in[1];
  const float* ln_kg = (const float*)d_in[2];
  const float* ln_kb = (const float*)d_in[3];
  const float* ln_qg = (const float*)d_in[4];
  const float* ln_qb = (const float*)d_in[5];
  const float* ln_vg = (const float*)d_in[6];
  const float* ln_vb = (const float*)d_in[7];
  const float* Wq = (const float*)d_in[8];
  const float* bq = (const float*)d_in[9];
  const float* Wk = (const float*)d_in[10];
  const float* bk = (const float*)d_in[11];
  const float* Wv = (const float*)d_in[12];
  const float* bv = (const float*)d_in[13];
  const float* Wo = (const float*)d_in[14];
  const float* bo = (const float*)d_in[15];
  const float* W1 = (const float*)d_in[16];
  const float* b1 = (const float*)d_in[17];
  const float* W2 = (const float*)d_in[18];
  const float* b2 = (const float*)d_in[19];

  float* out = (float*)d_out;  // [0..511] top indices (as float), then logits
  float* logits = out + BSZ * 4;

  float* ws = (float*)d_ws;
  size_t off = 0;
  auto alloc = [&](size_t n) { float* p = ws + off; off += n; return p; };
  const size_t ND2 = (size_t)NTOT * DMODEL / 2;  // one fp16 N*D buffer, in floats
  float* mb_mean = alloc(NTOT);
  float* mb_rstd = alloc(NTOT);
  float* mb_l2i  = alloc(NTOT);
  float* q_mean  = alloc(128);   // reused as rq stats scratch later
  float* q_rstd  = alloc(128);
  float* rq_inv  = alloc(128);
  float* pad_    = alloc(384);
  f16* k_hi = (f16*)alloc(ND2);  // [N][768] fp16
  f16* k_lo = (f16*)alloc(ND2);
  f16* v_hi = (f16*)alloc(ND2);
  f16* v_lo = (f16*)alloc(ND2);
  float* part_ml = alloc((size_t)NHEAD * FCHUNK * BSZ * 2);
  float* part_o  = alloc((size_t)NHEAD * FCHUNK * BSZ * 48);
  float* xi   = alloc((size_t)BSZ * DMODEL);
  float* conv = alloc((size_t)BSZ * DMODEL);
  float* comb = alloc((size_t)BSZ * DMODEL);
  float* h1   = alloc((size_t)BSZ * DMODEL);
  f16* xi_hi = (f16*)alloc((size_t)BSZ * DMODEL / 2);
  f16* xi_lo = (f16*)alloc((size_t)BSZ * DMODEL / 2);
  f16* Wc_hi = (f16*)alloc((size_t)2 * DMODEL * DMODEL / 2);  // [1536][768]
  f16* Wc_lo = (f16*)alloc((size_t)2 * DMODEL * DMODEL / 2);
  float* biasc = alloc(2 * DMODEL);
  (void)ws_size; (void)in_sizes; (void)n_in; (void)out_size; (void)pad_;

  // 1. stats + W prep
  row_stats<<<NTOT / 4, 256, 0, stream>>>(mb, NTOT, mb_mean, mb_rstd, mb_l2i);
  row_stats<<<BSZ / 4, 256, 0, stream>>>(qe, BSZ, q_mean, q_rstd, nullptr);
  prep_w<<<2 * DMODEL / 4, 256, 0, stream>>>(Wk, bk, ln_kg, ln_kb,
                                             Wv, bv, ln_vg, ln_vb,
                                             Wc_hi, Wc_lo, biasc);

  // 2. fused dual projection (k & v, hi/lo) via MFMA; q (xi) fp32
  proj_dual_mfma<<<dim3(2 * DMODEL / 128, NTOT / 128), 256, 0, stream>>>(
      mb, mb_mean, mb_rstd, Wc_hi, Wc_lo, biasc, k_hi, k_lo, v_hi, v_lo);
  ln_gemm_f32<<<dim3(DMODEL / 64, BSZ / 64), 256, 0, stream>>>(
      qe, q_mean, q_rstd, ln_qg, ln_qb, Wq, bq, xi);

  // 3. Hopfield: 5 updates (value = k), then readout (value = v)
  for (int r = 0; r < 6; r++) {
    const f16* valHi = (r == 5) ? v_hi : k_hi;
    const f16* valLo = (r == 5) ? v_lo : k_lo;
    float* dst = (r == 5) ? conv : xi;
    split_xi_k<<<96, 256, 0, stream>>>(xi, xi_hi, xi_lo);
    flash_round<<<dim3(FCHUNK, NHEAD), 256, 0, stream>>>(
        k_hi, k_lo, valHi, valLo, xi_hi, xi_lo, part_ml, part_o);
    hopfield_combine<<<BSZ * NHEAD, 64, 0, stream>>>(part_ml, part_o, dst);
  }

  // 4. readout MLP
  gemm_bias<<<dim3(DMODEL / 64, BSZ / 64), 256, 0, stream>>>(conv, Wo, bo, qe, comb, 0);
  gemm_bias<<<dim3(DMODEL / 64, BSZ / 64), 256, 0, stream>>>(comb, W1, b1, nullptr, h1, 1);
  float* rq = conv;  // conv dead after comb computed; reuse for rq
  gemm_bias<<<dim3(DMODEL / 64, BSZ / 64), 256, 0, stream>>>(h1, W2, b2, nullptr, rq, 0);

  // 5. cosine logits
  row_stats<<<BSZ / 4, 256, 0, stream>>>(rq, BSZ, q_mean, q_rstd, rq_inv);
  logits_gemm<<<dim3(NTOT / 64, BSZ / 64), 256, 0, stream>>>(rq, mb, rq_inv, mb_l2i, logits);

  // 6. top-4 indices
  topk_kernel<<<BSZ, 256, 0, stream>>>(logits, out);
}